// Round 1
// baseline (195.245 us; speedup 1.0000x reference)
//
#include <hip/hip_runtime.h>
#include <math.h>

// Problem constants (reference: B=16, C=256, H=80, W=80, K=3, ALPHA=0.1, EPS=1e-7)
#define L_LEN 6400        // H*W
#define NROWS 4096        // B*C
#define C_CH 256
#define TPB 320           // 5 waves of 64
#define VPT 20            // elements per thread
// log2(0.9) in float
#define LOG2_DECAY_F -0.15200309f

typedef float v4f __attribute__((ext_vector_type(4)));   // native vec4 (builtin-compatible)

// Async global->LDS prefetch of one full row (25.6 KB) in 5 wave-issues/thread.
// LDS dest must be wave-uniform base + lane*16 (m104/m108): our layout is
// lane-contiguous float4, so base = k*TPB + (t & ~63).
__device__ __forceinline__ void prefetch_row(const v4f* gsrc, v4f* ldst, int t) {
    const int wbase = t & ~63;
#pragma unroll
    for (int k = 0; k < 5; ++k) {
        __builtin_amdgcn_global_load_lds(
            (__attribute__((address_space(1))) void*)(gsrc + k * TPB + t),
            (__attribute__((address_space(3))) void*)(ldst + k * TPB + wbase),
            16, 0, 0);
    }
}

// One row per block: single 25.6 KB LDS buffer -> 6 blocks/CU (thread-limited),
// direct register stores (no output LDS round-trip, one fewer barrier).
__global__ __launch_bounds__(TPB) void ema_attn_kernel(
    const float* __restrict__ x,
    const float* __restrict__ conv_w,   // [C,1,3]
    const float* __restrict__ conv_b,   // [C]
    float* __restrict__ out)
{
    __shared__ __align__(16) float sbuf[L_LEN];   // 25.6 KB single buffer
    __shared__ float wsum[TPB / 64];

    const int row  = blockIdx.x;         // GRID == NROWS, one row per block
    const int t    = threadIdx.x;
    const int lane = t & 63;
    const int wid  = t >> 6;
    const int start = t * VPT;
    const int c    = row & (C_CH - 1);   // row = b*C + c

    // issue the async row load first; scalar params load under it
    prefetch_row((const v4f*)(x + (long)row * L_LEN), (v4f*)sbuf, t);

    const float w0   = conv_w[c * 3 + 0];
    const float w1   = conv_w[c * 3 + 1];
    const float w2   = conv_w[c * 3 + 2];
    const float bias = conv_b[c];

    // 0.9^start; for start beyond ~990 reference f32 decay underflows to 0 anyway
    const float d0 = exp2f((float)start * LOG2_DECAY_F);

    __syncthreads();   // drains vmcnt -> row resident in LDS

    // ---- pass 1: chunk + conv neighbors from LDS, weighted local dot ----
    float xv[VPT];
    const v4f* my4 = (const v4f*)(sbuf + start);
#pragma unroll
    for (int i = 0; i < 5; ++i) {
        v4f v = my4[i];
        xv[4*i+0] = v.x; xv[4*i+1] = v.y; xv[4*i+2] = v.z; xv[4*i+3] = v.w;
    }
    const float xl = (start == 0)           ? 0.f : sbuf[start - 1];
    const float xr = (start + VPT == L_LEN) ? 0.f : sbuf[start + VPT];

    float p = 0.f, w = 0.1f;            // w = 0.1*0.9^j, constant-folded chain
#pragma unroll
    for (int j = 0; j < VPT; ++j) { p = fmaf(xv[j], w, p); w *= 0.9f; }
    const float s = d0 * p;

    // ---- block scan of thread sums ----
    float inc = s;
#pragma unroll
    for (int off = 1; off < 64; off <<= 1) {
        float n = __shfl_up(inc, off, 64);
        if (lane >= off) inc += n;
    }
    if (lane == 63) wsum[wid] = inc;
    __syncthreads();                    // scan partials visible

    float excl = inc - s;
#pragma unroll
    for (int wp = 0; wp < TPB / 64; ++wp)
        if (wp < wid) excl += wsum[wp];

    // ---- pass 2: ema + conv + residual, stored straight from registers ----
    // Per-instruction lanes stride 80 B, but each wave's 5 stores cover a
    // contiguous 5 KB span back-to-back -> L2 write-combines to full lines.
    v4f* go = (v4f*)(out + (long)row * L_LEN + start);
    float pj = 0.f; w = 0.1f;
#pragma unroll
    for (int i = 0; i < 5; ++i) {
        v4f ov;
#pragma unroll
        for (int q = 0; q < 4; ++q) {
            const int j = 4*i + q;
            pj = fmaf(xv[j], w, pj);                       // partial weighted dot
            float cum = fmaf(d0, pj, excl);
            float cd  = fmaf(-d0, 9.0f * w, 1.0f) + 1e-7f; // 1 - 0.9^(start+j+1) + eps
            float ema = cum * __builtin_amdgcn_rcpf(cd);
            float prev = (j == 0)       ? xl : xv[j-1];
            float nx   = (j == VPT-1)   ? xr : xv[j+1];
            float conv = fmaf(w0, prev, fmaf(w1, xv[j], fmaf(w2, nx, bias)));
            ov[q] = ema + conv + xv[j];
            w *= 0.9f;
        }
        __builtin_nontemporal_store(ov, go + i);
    }
}

extern "C" void kernel_launch(void* const* d_in, const int* in_sizes, int n_in,
                              void* d_out, int out_size, void* d_ws, size_t ws_size,
                              hipStream_t stream) {
    const float* x      = (const float*)d_in[0];
    const float* conv_w = (const float*)d_in[1];
    const float* conv_b = (const float*)d_in[2];
    float* out          = (float*)d_out;
    ema_attn_kernel<<<NROWS, TPB, 0, stream>>>(x, conv_w, conv_b, out);
}

// Round 2
// 36.402 us; speedup vs baseline: 5.3635x; 5.3635x over previous
//
#include <hip/hip_runtime.h>
#include <math.h>

// Problem constants (reference: B=16, C=256, H=80, W=80, K=3, ALPHA=0.1, EPS=1e-7)
#define L_LEN 6400        // H*W
#define NROWS 4096        // B*C
#define C_CH 256
#define TPB 320           // 5 waves of 64
#define VPT 20            // elements per thread
// log2(0.9) in float
#define LOG2_DECAY_F -0.15200309f

typedef float v4f __attribute__((ext_vector_type(4)));   // native vec4 (builtin-compatible)

// Async global->LDS prefetch of one full row (25.6 KB) in 5 wave-issues/thread.
// LDS dest must be wave-uniform base + lane*16 (m104/m108): our layout is
// lane-contiguous float4, so base = k*TPB + (t & ~63).
__device__ __forceinline__ void prefetch_row(const v4f* gsrc, v4f* ldst, int t) {
    const int wbase = t & ~63;
#pragma unroll
    for (int k = 0; k < 5; ++k) {
        __builtin_amdgcn_global_load_lds(
            (__attribute__((address_space(1))) void*)(gsrc + k * TPB + t),
            (__attribute__((address_space(3))) void*)(ldst + k * TPB + wbase),
            16, 0, 0);
    }
}

// One row per block (6 blocks/CU, thread-limited occupancy) + LDS-staged output
// so the HBM store is the proven lane-contiguous 16B/lane pattern (R0: zero
// write amplification; R1's direct strided nt-stores hit 3x WRITE_SIZE).
__global__ __launch_bounds__(TPB) void ema_attn_kernel(
    const float* __restrict__ x,
    const float* __restrict__ conv_w,   // [C,1,3]
    const float* __restrict__ conv_b,   // [C]
    float* __restrict__ out)
{
    __shared__ __align__(16) float sbuf[L_LEN];   // 25.6 KB single buffer
    __shared__ float wsum[TPB / 64];

    const int row  = blockIdx.x;         // GRID == NROWS, one row per block
    const int t    = threadIdx.x;
    const int lane = t & 63;
    const int wid  = t >> 6;
    const int start = t * VPT;
    const int c    = row & (C_CH - 1);   // row = b*C + c

    // issue the async row load first; scalar params load under it
    prefetch_row((const v4f*)(x + (long)row * L_LEN), (v4f*)sbuf, t);

    const float w0   = conv_w[c * 3 + 0];
    const float w1   = conv_w[c * 3 + 1];
    const float w2   = conv_w[c * 3 + 2];
    const float bias = conv_b[c];

    // 0.9^start; for start beyond ~990 reference f32 decay underflows to 0 anyway
    const float d0 = exp2f((float)start * LOG2_DECAY_F);

    __syncthreads();   // drains vmcnt -> row resident in LDS

    // ---- pass 1: chunk + conv neighbors from LDS, weighted local dot ----
    float xv[VPT];
    const v4f* my4 = (const v4f*)(sbuf + start);
#pragma unroll
    for (int i = 0; i < 5; ++i) {
        v4f v = my4[i];
        xv[4*i+0] = v.x; xv[4*i+1] = v.y; xv[4*i+2] = v.z; xv[4*i+3] = v.w;
    }
    const float xl = (start == 0)           ? 0.f : sbuf[start - 1];
    const float xr = (start + VPT == L_LEN) ? 0.f : sbuf[start + VPT];

    float p = 0.f, w = 0.1f;            // w = 0.1*0.9^j, constant-folded chain
#pragma unroll
    for (int j = 0; j < VPT; ++j) { p = fmaf(xv[j], w, p); w *= 0.9f; }
    const float s = d0 * p;

    // ---- block scan of thread sums ----
    float inc = s;
#pragma unroll
    for (int off = 1; off < 64; off <<= 1) {
        float n = __shfl_up(inc, off, 64);
        if (lane >= off) inc += n;
    }
    if (lane == 63) wsum[wid] = inc;
    __syncthreads();                    // barrier 1: scan partials + all sbuf reads done

    float excl = inc - s;
#pragma unroll
    for (int wp = 0; wp < TPB / 64; ++wp)
        if (wp < wid) excl += wsum[wp];

    // ---- pass 2: ema + conv + residual, outputs staged back into sbuf ----
    float o[VPT];
    float pj = 0.f; w = 0.1f;
#pragma unroll
    for (int j = 0; j < VPT; ++j) {
        pj = fmaf(xv[j], w, pj);                       // partial weighted dot
        float cum = fmaf(d0, pj, excl);
        float cd  = fmaf(-d0, 9.0f * w, 1.0f) + 1e-7f; // 1 - 0.9^(start+j+1) + eps
        float ema = cum * __builtin_amdgcn_rcpf(cd);
        float prev = (j == 0)       ? xl : xv[j-1];
        float nx   = (j == VPT-1)   ? xr : xv[j+1];
        float conv = fmaf(w0, prev, fmaf(w1, xv[j], fmaf(w2, nx, bias)));
        o[j] = ema + conv + xv[j];
        w *= 0.9f;
    }
    v4f* my4w = (v4f*)(sbuf + start);
#pragma unroll
    for (int i = 0; i < 5; ++i) {
        v4f ov = { o[4*i+0], o[4*i+1], o[4*i+2], o[4*i+3] };
        my4w[i] = ov;
    }
    __syncthreads();                    // barrier 2: staged outputs visible

    // ---- coalesced nontemporal store from LDS (16B/lane, fully sequential) ----
    v4f* go = (v4f*)(out + (long)row * L_LEN);
    const v4f* c4 = (const v4f*)sbuf;
#pragma unroll
    for (int k = 0; k < 5; ++k)
        __builtin_nontemporal_store(c4[k * TPB + t], go + k * TPB + t);
}

extern "C" void kernel_launch(void* const* d_in, const int* in_sizes, int n_in,
                              void* d_out, int out_size, void* d_ws, size_t ws_size,
                              hipStream_t stream) {
    const float* x      = (const float*)d_in[0];
    const float* conv_w = (const float*)d_in[1];
    const float* conv_b = (const float*)d_in[2];
    float* out          = (float*)d_out;
    ema_attn_kernel<<<NROWS, TPB, 0, stream>>>(x, conv_w, conv_b, out);
}

// Round 3
// 36.190 us; speedup vs baseline: 5.3949x; 1.0059x over previous
//
#include <hip/hip_runtime.h>
#include <math.h>

// Problem constants (reference: B=16, C=256, H=80, W=80, K=3, ALPHA=0.1, EPS=1e-7)
#define L_LEN 6400        // H*W
#define NROWS 4096        // B*C
#define C_CH 256
#define TPB 320           // 5 waves of 64
#define VPT 20            // elements per thread
#define WPB (TPB / 64)    // 5 waves per block
#define F4W 320           // float4s per wave slice (64 lanes * 5)
// log2(0.9) in float
#define LOG2_DECAY_F -0.15200309f

typedef float v4f __attribute__((ext_vector_type(4)));

// One row per block, but ALL memory phases are wave-local:
//  - each wave DMAs its own 5 KB slice (global_load_lds, uniform dest base)
//    and waits with its own vmcnt(0) -- no block barrier for load readiness
//  - conv boundary elements come from global, not neighbor-wave LDS
//  - output transpose stays inside the wave's own slice -> lgkmcnt(0), no barrier
// The only block-wide sync left is the cross-wave scan exchange.
__global__ __launch_bounds__(TPB) void ema_attn_kernel(
    const float* __restrict__ x,
    const float* __restrict__ conv_w,   // [C,1,3]
    const float* __restrict__ conv_b,   // [C]
    float* __restrict__ out)
{
    __shared__ __align__(16) float sbuf[L_LEN];   // 25.6 KB
    __shared__ float wsum[WPB];

    const int row  = blockIdx.x;         // GRID == NROWS
    const int t    = threadIdx.x;
    const int lane = t & 63;
    const int wid  = t >> 6;
    const int start = t * VPT;
    const int c    = row & (C_CH - 1);   // row = b*C + c

    const long rowbase = (long)row * L_LEN;
    const v4f* gsrc = (const v4f*)(x + rowbase);
    v4f* lbase = (v4f*)sbuf;

    // per-wave DMA of own slice: LDS dest = wave-uniform base (HW adds lane*16),
    // global src = per-lane address. Identity mapping within the slice.
#pragma unroll
    for (int k = 0; k < 5; ++k) {
        __builtin_amdgcn_global_load_lds(
            (__attribute__((address_space(1))) void*)(gsrc + wid * F4W + k * 64 + lane),
            (__attribute__((address_space(3))) void*)(lbase + wid * F4W + k * 64),
            16, 0, 0);
    }

    // conv neighbors straight from global (L2-hot: same lines the DMA streams)
    const int il = (start == 0) ? 0 : start - 1;
    const int ir = (start + VPT >= L_LEN) ? (L_LEN - 1) : (start + VPT);
    float gxl = x[rowbase + il];
    float gxr = x[rowbase + ir];
    if (start == 0) gxl = 0.f;
    if (start + VPT >= L_LEN) gxr = 0.f;

    const float w0   = conv_w[c * 3 + 0];
    const float w1   = conv_w[c * 3 + 1];
    const float w2   = conv_w[c * 3 + 2];
    const float bias = conv_b[c];

    // 0.9^start
    const float d0 = exp2f((float)start * LOG2_DECAY_F);

    // wait own-wave VMEM only (5 DMA + 2 neighbor loads); no block barrier
    asm volatile("s_waitcnt vmcnt(0)" ::: "memory");

    // ---- pass 1: own slice from LDS, weighted local dot ----
    float xv[VPT];
    const v4f* my4 = (const v4f*)(sbuf + start);
#pragma unroll
    for (int i = 0; i < 5; ++i) {
        v4f v = my4[i];
        xv[4*i+0] = v.x; xv[4*i+1] = v.y; xv[4*i+2] = v.z; xv[4*i+3] = v.w;
    }

    float p = 0.f, w = 0.1f;            // w = 0.1*0.9^j, constant-folded chain
#pragma unroll
    for (int j = 0; j < VPT; ++j) { p = fmaf(xv[j], w, p); w *= 0.9f; }
    const float s = d0 * p;

    // ---- block scan of thread sums (sole block-wide sync) ----
    float inc = s;
#pragma unroll
    for (int off = 1; off < 64; off <<= 1) {
        float n = __shfl_up(inc, off, 64);
        if (lane >= off) inc += n;
    }
    if (lane == 63) wsum[wid] = inc;
    __syncthreads();

    float excl = inc - s;
#pragma unroll
    for (int wp = 0; wp < WPB; ++wp)
        if (wp < wid) excl += wsum[wp];

    // ---- pass 2: ema + conv + residual, staged into OWN wave slice ----
    float o[VPT];
    float pj = 0.f; w = 0.1f;
#pragma unroll
    for (int j = 0; j < VPT; ++j) {
        pj = fmaf(xv[j], w, pj);                       // partial weighted dot
        float cum = fmaf(d0, pj, excl);
        float cd  = fmaf(-d0, 9.0f * w, 1.0f) + 1e-7f; // 1 - 0.9^(start+j+1) + eps
        float ema = cum * __builtin_amdgcn_rcpf(cd);
        float prev = (j == 0)       ? gxl : xv[j-1];
        float nx   = (j == VPT-1)   ? gxr : xv[j+1];
        float conv = fmaf(w0, prev, fmaf(w1, xv[j], fmaf(w2, nx, bias)));
        o[j] = ema + conv + xv[j];
        w *= 0.9f;
    }
    v4f* my4w = (v4f*)(sbuf + start);
#pragma unroll
    for (int i = 0; i < 5; ++i) {
        v4f ov = { o[4*i+0], o[4*i+1], o[4*i+2], o[4*i+3] };
        my4w[i] = ov;
    }

    // wave-local transpose visibility: own writes -> own (cross-lane) reads
    asm volatile("s_waitcnt lgkmcnt(0)" ::: "memory");

    // ---- coalesced nontemporal store of own slice (16B/lane sequential) ----
    v4f* go = (v4f*)(out + rowbase);
#pragma unroll
    for (int k = 0; k < 5; ++k) {
        const int i4 = wid * F4W + k * 64 + lane;
        __builtin_nontemporal_store(lbase[i4], go + i4);
    }
}

extern "C" void kernel_launch(void* const* d_in, const int* in_sizes, int n_in,
                              void* d_out, int out_size, void* d_ws, size_t ws_size,
                              hipStream_t stream) {
    const float* x      = (const float*)d_in[0];
    const float* conv_w = (const float*)d_in[1];
    const float* conv_b = (const float*)d_in[2];
    float* out          = (float*)d_out;
    ema_attn_kernel<<<NROWS, TPB, 0, stream>>>(x, conv_w, conv_b, out);
}